// Round 9
// baseline (255.059 us; speedup 1.0000x reference)
//
#include <hip/hip_runtime.h>

typedef unsigned int u32;
typedef unsigned short u16;

#define NT 128
#define NBLK 2500

typedef __attribute__((ext_vector_type(8))) short bh8;
typedef __attribute__((ext_vector_type(4))) float f4;
union U8 { uint4 u; bh8 h; };

__device__ __forceinline__ u16 fb(float x){            // fp32->bf16 RNE (used by prep)
    u32 u = __float_as_uint(x);
    u += 0x7fffu + ((u>>16)&1u);
    return (u16)(u>>16);
}
// pack two f32 -> two bf16 in one VALU op (RNE, same as fb): lo=a, hi=b
__device__ __forceinline__ u32 pk2(float a, float b){
    u32 r;
    __asm__("v_cvt_pk_bf16_f32 %0, %1, %2" : "=v"(r) : "v"(a), "v"(b));
    return r;
}
__device__ __forceinline__ float bf_lo(u32 w){ return __uint_as_float(w<<16); }
__device__ __forceinline__ float bf_hi(u32 w){ return __uint_as_float(w & 0xffff0000u); }

// tanh-form gelu (R7/R8 verified): ~10 VALU + 2 trans; deviation from
// erf-form <= ~4e-4, under the bf16 quantization applied right after.
__device__ __forceinline__ float gelu(float x){
    float x2 = x*x;
    float y  = x * fmaf(0.0356774081f, x2, 0.7978845608f);  // sqrt(2/pi)(x+0.044715x^3)
    float t  = __expf(-2.0f * fabsf(y));                    // e^{-2|y|}
    float r  = __builtin_amdgcn_rcpf(1.0f + t);             // raw v_rcp_f32 (~1ulp)
    float m  = t * r;
    float th = fmaf(-2.0f, m, 1.0f);                        // tanh(|y|)
    float hx = 0.5f * x;
    return fmaf(fabsf(hx), th, hx);                         // 0.5x + 0.5|x|tanh(|y|)
}

// ---------- prep: pack W1^T / W2^T (k and v) into MFMA A-frag order, bf16 ----
// ws16 layout (u16): [A1K:2048][A1V:2048][A2K:16384][A2V:16384]
// ROUND-9: A1's M-row -> W1-channel map is PERMUTED so MFMA1's D layout
// (lane(q,r) holds rows q*4+i) directly yields MFMA2's B-frag layout
// (lane(q,r) holds chans q*8..q*8+7 across tile pairs):
//   chan(mt, ml) = (mt>>1)*32 + (mt&1)*4 + (ml>>2)*8 + (ml&3)   [bijection]
// This removes the LDS h-bounce + both hard fences in the conv entirely.
// A2 is unchanged (it indexes true channels).
__global__ void prep_pack(const float* __restrict__ kw1, const float* __restrict__ vw1,
                          const float* __restrict__ kw2, const float* __restrict__ vw2,
                          u16* __restrict__ ws16)
{
    int t = blockIdx.x*256 + threadIdx.x;        // 0..36863
    if (t >= 36864) return;
    float val;
    if (t < 4096){
        const float* w1 = (t < 2048) ? kw1 : vw1;
        int u = t & 2047;
        int mt = u >> 9, lane = (u>>3)&63, j = u&7;
        int ml = lane & 15;
        int chan = ((mt>>1)<<5) + ((mt&1)<<2) + ((ml>>2)<<3) + (ml&3);
        int x = (lane>>4)*8 + j;
        val = w1[x*64 + chan];
    } else {
        int s2 = t - 4096;
        const float* w2 = (s2 < 16384) ? kw2 : vw2;
        int u = s2 & 16383;
        int blkidx = u >> 9;                      // mt*2+s
        int mt = blkidx >> 1, s = blkidx & 1;
        int lane = (u>>3)&63, j = u&7;
        int ij = mt*16 + (lane&15);
        int c  = s*32 + (lane>>4)*8 + j;
        val = w2[c*256 + ij];
    }
    ws16[t] = fb(val);
}

// ---------- one radial conv via MFMA: t2[16] stays in registers ------------
// ROUND-9: staging is now 100% in-register (channel-permuted A1, see prep):
// per pair tile, 4x {MFMA1 -> bias -> gelu -> cvt_pk} produce 8 u32 that ARE
// the two B-frags (tiles 0,1 -> b2f0 chans 0..31; tiles 2,3 -> b2f1 chans
// 32..63). No LDS writes, no lgkmcnt fences, sHT deleted.
// Invariants (round-5 + round-1 lessons):
//  - every loop indexing a register array MUST fully unroll;
//  - t2v is written UNCONDITIONALLY via selects (v_cndmask), never under a
//    divergent `if`.
__device__ __forceinline__ void conv_mfma(
    const u16* __restrict__ pA1, const u16* __restrict__ pA2,
    const float* __restrict__ b1g, const float* __restrict__ b2g,
    const bh8* __restrict__ B1f,          // [4] cached ef frags
    const u32* __restrict__ tmpS,         // stride 10 u32 rows (16 bf16)
    float* __restrict__ t2v,              // [16] regs out
    int w, int lane)
{
    const int r = lane & 15, q = lane >> 4;

    #pragma unroll
    for (int mt=0; mt<16; ++mt) t2v[mt] = 0.f;

    // hoisted W1-bias rows under the permuted channel map:
    // tile mt bias chans = (mt>>1)*32 + (mt&1)*4 + q*8 + i
    float4 bva0 = *(const float4*)(b1g +      q*8);      // mt=0
    float4 bva1 = *(const float4*)(b1g +      q*8 + 4);  // mt=1
    float4 bva2 = *(const float4*)(b1g + 32 + q*8);      // mt=2
    float4 bva3 = *(const float4*)(b1g + 32 + q*8 + 4);  // mt=3

    #pragma unroll
    for (int ntp=0; ntp<2; ++ntp){
        bh8 b2f0[2], b2f1[2];
        float tm[2][4];

        // ---- staging: both pair tiles, entirely in registers ----
        #pragma unroll
        for (int b=0; b<2; ++b){
            const int nt = ntp*2 + b;
            u32 hw0, hw1, hw2, hw3, hw4, hw5, hw6, hw7;
            #pragma unroll
            for (int mt=0; mt<4; ++mt){
                bh8 a1 = *(const bh8*)(pA1 + ((mt*64 + lane)<<3));
                f4 d1 = {0.f,0.f,0.f,0.f};
                d1 = __builtin_amdgcn_mfma_f32_16x16x32_bf16(a1, B1f[nt], d1, 0,0,0);
                float4 bv = (mt==0)?bva0:(mt==1)?bva1:(mt==2)?bva2:bva3;
                float g0 = gelu(d1[0]+bv.x), g1 = gelu(d1[1]+bv.y);
                float g2 = gelu(d1[2]+bv.z), g3 = gelu(d1[3]+bv.w);
                u32 lo = pk2(g0,g1), hi = pk2(g2,g3);
                if (mt==0){ hw0=lo; hw1=hi; }
                else if (mt==1){ hw2=lo; hw3=hi; }
                else if (mt==2){ hw4=lo; hw5=hi; }
                else { hw6=lo; hw7=hi; }
            }
            U8 u0; u0.u = make_uint4(hw0,hw1,hw2,hw3); b2f0[b] = u0.h;  // chans q*8..+7
            U8 u1; u1.u = make_uint4(hw4,hw5,hw6,hw7); b2f1[b] = u1.h;  // chans 32+q*8..+7
            const int ntg = w*4 + nt;
            uint2 tp = *(const uint2*)(tmpS + (ntg*16 + r)*10 + q*2);
            tm[b][0]=bf_lo(tp.x); tm[b][1]=bf_hi(tp.x);
            tm[b][2]=bf_lo(tp.y); tm[b][3]=bf_hi(tp.y);
        }

        // ---- main: all 16 ij-tiles, both pair tiles inner ----
        #pragma unroll
        for (int mt=0; mt<16; ++mt){
            bh8 a2s0 = *(const bh8*)(pA2 + (((mt*2+0)*64 + lane)<<3));
            bh8 a2s1 = *(const bh8*)(pA2 + (((mt*2+1)*64 + lane)<<3));
            float4 bv = *(const float4*)(b2g + mt*16 + q*4);
            float pb0, pb1;
            {
                f4 acc = {0.f,0.f,0.f,0.f};
                acc = __builtin_amdgcn_mfma_f32_16x16x32_bf16(a2s0, b2f0[0], acc, 0,0,0);
                acc = __builtin_amdgcn_mfma_f32_16x16x32_bf16(a2s1, b2f1[0], acc, 0,0,0);
                float p = (acc[0]+bv.x)*tm[0][0] + (acc[1]+bv.y)*tm[0][1]
                        + (acc[2]+bv.z)*tm[0][2] + (acc[3]+bv.w)*tm[0][3];
                p += __shfl_xor(p, 16);
                p += __shfl_xor(p, 32);
                pb0 = p;
            }
            {
                f4 acc = {0.f,0.f,0.f,0.f};
                acc = __builtin_amdgcn_mfma_f32_16x16x32_bf16(a2s0, b2f0[1], acc, 0,0,0);
                acc = __builtin_amdgcn_mfma_f32_16x16x32_bf16(a2s1, b2f1[1], acc, 0,0,0);
                float p = (acc[0]+bv.x)*tm[1][0] + (acc[1]+bv.y)*tm[1][1]
                        + (acc[2]+bv.z)*tm[1][2] + (acc[3]+bv.w)*tm[1][3];
                p += __shfl_xor(p, 16);
                p += __shfl_xor(p, 32);
                pb1 = p;
            }
            // owner lane of edge (w*4+nt)*16+r is (q=nt, r); nt = ntp*2 + (q&1)
            float sel = (q & 1) ? pb1 : pb0;
            t2v[mt] = ((q >> 1) == ntp) ? sel : t2v[mt];
        }
    }
}

// ---------------- fused main kernel -------------------------------------------
// ROUND-9 = R8 (92us) minus the conv LDS bounce: channel-permuted A1 pack
// makes MFMA1 output land directly in MFMA2 B-frag layout (register-only
// staging, zero conv fences), and sHT is deleted: LDS 35840 -> 26624 B
// => 6 blocks/CU cap (was 4). launch_bounds(128,1): allocator unconstrained
// (history: arg2=2 capped arch VGPRs at 128 -> 950B/thread spill).
__global__ __launch_bounds__(NT, 1) void eqattn_main(
    const float* __restrict__ bk1, const float* __restrict__ bk2,
    const float* __restrict__ bv1, const float* __restrict__ bv2,
    const float* __restrict__ efg, const float* __restrict__ fg,
    const float* __restrict__ qw,  const float* __restrict__ qb,
    const float* __restrict__ kb1, const float* __restrict__ kb2,
    const float* __restrict__ vb1, const float* __restrict__ vb2,
    const float* __restrict__ ow,  const float* __restrict__ ob,
    const int* __restrict__ nidx,  const u16* __restrict__ ws16,
    float* __restrict__ outg)
{
    __shared__ __align__(16) u32 sTmpK[1280];  // 5120: tmp-k bf16 rows (stride 10 u32) -> attn scratch
    __shared__ __align__(16) u32 sTmpV[1280];  // 5120: tmp-v bf16 rows
    __shared__ __align__(16) u32 sKS [2048];   // 8192: k rows 16 u32 (pair-swizzled)
    __shared__ __align__(16) u32 sVS [2048];   // 8192: v rows
    // sHT deleted (register staging). LDS total 26624 B.

    const int t    = threadIdx.x;
    const int lane = t & 63;
    const int w    = t >> 6;
    const int r    = lane & 15, q = lane >> 4;
    const int n0   = blockIdx.x * 8;
    const int e    = blockIdx.x * 128 + t;

    const u16* pA1k = ws16;
    const u16* pA1v = ws16 + 2048;
    const u16* pA2k = ws16 + 4096;
    const u16* pA2v = ws16 + 20480;

    // ---- phase 0: gather f[src], tmpk/tmpv (bf16 rows) ----
    {
        int src = nidx[e];
        const float4* fr = (const float4*)(fg + src*32);
        float fs[32];
        #pragma unroll
        for (int i=0;i<8;++i){
            float4 v = fr[i];
            fs[i*4]=v.x; fs[i*4+1]=v.y; fs[i*4+2]=v.z; fs[i*4+3]=v.w;
        }
        float4 ka = *(const float4*)(bk1+e*8), kbv = *(const float4*)(bk1+e*8+4);
        float4 va = *(const float4*)(bv1+e*8), vbv = *(const float4*)(bv1+e*8+4);
        float b1k[8] = {ka.x,ka.y,ka.z,ka.w,kbv.x,kbv.y,kbv.z,kbv.w};
        float b1v[8] = {va.x,va.y,va.z,va.w,vbv.x,vbv.y,vbv.z,vbv.w};
        float tk[16], tv[16];
        #pragma unroll
        for (int m=0;m<8;++m){
            float t0=0.f,t1=0.f,u0=0.f,u1=0.f;
            #pragma unroll
            for (int d=0;d<4;++d){
                float fv = fs[m*4+d];
                t0 += fv*b1k[d*2];  t1 += fv*b1k[d*2+1];
                u0 += fv*b1v[d*2];  u1 += fv*b1v[d*2+1];
            }
            tk[m*2]=t0; tk[m*2+1]=t1; tv[m*2]=u0; tv[m*2+1]=u1;
        }
        #pragma unroll
        for (int i=0;i<8;++i){
            sTmpK[t*10+i] = pk2(tk[i*2], tk[i*2+1]);
            sTmpV[t*10+i] = pk2(tv[i*2], tv[i*2+1]);
        }
    }

    // ---- B1 frags: ef rows -> bf16 (shared by K and V convs) ----
    bh8 B1f[4];
    #pragma unroll
    for (int nt=0; nt<4; ++nt){
        int eg = blockIdx.x*128 + (w*4+nt)*16 + r;
        float4 ea = *(const float4*)(efg + eg*32 + q*8);
        float4 eb = *(const float4*)(efg + eg*32 + q*8 + 4);
        U8 uu;
        uu.u.x = pk2(ea.x, ea.y); uu.u.y = pk2(ea.z, ea.w);
        uu.u.z = pk2(eb.x, eb.y); uu.u.w = pk2(eb.z, eb.w);
        B1f[nt] = uu.h;
    }
    // fence: phase-0 sTmp writes (same wave, cross-lane) must land before
    // the convs' tm reads below. Single fence for both convs.
    __asm__ volatile("s_waitcnt lgkmcnt(0)" ::: "memory");

    // ---- K conv ----
    float t2k[16];
    conv_mfma(pA1k, pA2k, kb1, kb2, B1f, sTmpK, t2k, w, lane);
    {
        float4 c0 = *(const float4*)(bk2 + e*8);
        float4 c1 = *(const float4*)(bk2 + e*8 + 4);
        #pragma unroll
        for (int m=0;m<8;++m){
            float t20 = t2k[2*m], t21 = t2k[2*m+1];
            uint2 pk;
            pk.x = pk2(t20*c0.x + t21*c1.x, t20*c0.y + t21*c1.y);
            pk.y = pk2(t20*c0.z + t21*c1.z, t20*c0.w + t21*c1.w);
            *(uint2*)(sKS + t*16 + ((m ^ (t&7))<<1)) = pk;
        }
    }
    // ---- V conv ----
    float t2va[16];
    conv_mfma(pA1v, pA2v, vb1, vb2, B1f, sTmpV, t2va, w, lane);
    {
        float4 c0 = *(const float4*)(bv2 + e*8);
        float4 c1 = *(const float4*)(bv2 + e*8 + 4);
        #pragma unroll
        for (int m=0;m<8;++m){
            float t20 = t2va[2*m], t21 = t2va[2*m+1];
            uint2 pk;
            pk.x = pk2(t20*c0.x + t21*c1.x, t20*c0.y + t21*c1.y);
            pk.y = pk2(t20*c0.z + t21*c1.z, t20*c0.w + t21*c1.w);
            *(uint2*)(sVS + t*16 + ((m ^ (t&7))<<1)) = pk;
        }
    }
    __syncthreads();

    float* qS  = (float*)sTmpK;        // [8][33] = 264 floats
    float* lg  = (float*)sTmpK + 264;  // [32][17] = 544 floats
    float* aoS = (float*)sTmpK + 808;  // [8][33] = 264 floats (1072 <= 1280)

    // ---- q = eq_linear(f, q_w, q_b): 256 tasks ----
    #pragma unroll 1
    for (int p=0;p<2;++p){
        int task = p*NT + t;
        int ln = task>>5, m=(task>>2)&7, d=task&3;
        const float* frow = fg + (n0+ln)*32;
        int rr = ((d>0)?8:0) + m;
        float acc = (d==0) ? qb[m] : 0.f;
        #pragma unroll
        for (int mm=0;mm<8;++mm) acc += qw[rr*8+mm]*frow[mm*4+d];
        qS[ln*33 + m*4 + d] = acc;
    }
    __syncthreads();

    // ---- logits: 512 tasks ----
    #pragma unroll 1
    for (int p=0;p<4;++p){
        int task = p*NT + t;
        int ln = task>>6, hh=(task>>4)&3, k=task&15;
        int row = ln*16 + k;
        const float* qr = qS + ln*33 + hh*8;
        uint2 k0 = *(const uint2*)(sKS + row*16 + (((hh<<1)     ^ (row&7))<<1));
        uint2 k1 = *(const uint2*)(sKS + row*16 + ((((hh<<1)|1) ^ (row&7))<<1));
        float acc = qr[0]*bf_lo(k0.x)+qr[1]*bf_hi(k0.x)
                  + qr[2]*bf_lo(k0.y)+qr[3]*bf_hi(k0.y)
                  + qr[4]*bf_lo(k1.x)+qr[5]*bf_hi(k1.x)
                  + qr[6]*bf_lo(k1.y)+qr[7]*bf_hi(k1.y);
        lg[(ln*4+hh)*17 + k] = acc * 0.35355339059327373f;
    }
    __syncthreads();

    // ---- softmax over 16 neighbors: parallel (4 lanes/row, all 128 threads;
    // shfl groups stay inside one wave) ----
    {
        int row = t >> 2, sub = t & 3;
        float* rp = lg + row*17 + sub*4;
        float a0=rp[0], a1=rp[1], a2=rp[2], a3=rp[3];
        float mx = fmaxf(fmaxf(a0,a1), fmaxf(a2,a3));
        mx = fmaxf(mx, __shfl_xor(mx, 1));
        mx = fmaxf(mx, __shfl_xor(mx, 2));
        float e0=__expf(a0-mx), e1=__expf(a1-mx);
        float e2=__expf(a2-mx), e3=__expf(a3-mx);
        float s = (e0+e1)+(e2+e3);
        s += __shfl_xor(s, 1);
        s += __shfl_xor(s, 2);
        float inv = __builtin_amdgcn_rcpf(s);
        // one Newton step to keep softmax normalization at fp32 accuracy
        inv = inv * (2.0f - s*inv);
        rp[0]=e0*inv; rp[1]=e1*inv; rp[2]=e2*inv; rp[3]=e3*inv;
    }
    __syncthreads();

    // ---- attention output: 256 tasks ----
    #pragma unroll 1
    for (int p=0;p<2;++p){
        int task = p*NT + t;
        int ln = task>>5, comp = task&31, hh = comp>>3;
        const float* ar = lg + (ln*4+hh)*17;
        float acc=0.f;
        #pragma unroll
        for (int k=0;k<16;++k){
            int row = ln*16 + k;
            u32 wv = sVS[row*16 + (((comp>>2) ^ (row&7))<<1) + ((comp>>1)&1)];
            acc += ar[k] * ((comp&1) ? bf_hi(wv) : bf_lo(wv));
        }
        aoS[ln*33 + comp] = acc;
    }
    __syncthreads();

    // ---- final eq_linear(o_w, o_b) -> fp32 out ----
    #pragma unroll 1
    for (int p=0;p<2;++p){
        int task = p*NT + t;
        int ln = task>>5, m=(task>>2)&7, d=task&3;
        int rr = ((d>0)?8:0) + m;
        float acc = (d==0) ? ob[m] : 0.f;
        #pragma unroll
        for (int mm=0;mm<8;++mm) acc += ow[rr*8+mm]*aoS[ln*33 + mm*4 + d];
        outg[(n0+ln)*32 + m*4 + d] = acc;
    }
}

extern "C" void kernel_launch(void* const* d_in, const int* in_sizes, int n_in,
                              void* d_out, int out_size, void* d_ws, size_t ws_size,
                              hipStream_t stream)
{
    (void)in_sizes; (void)n_in; (void)out_size; (void)ws_size;
    const float* bk1 = (const float*)d_in[0];
    const float* bk2 = (const float*)d_in[1];
    const float* bv1 = (const float*)d_in[2];
    const float* bv2 = (const float*)d_in[3];
    const float* efg = (const float*)d_in[4];
    const float* fg  = (const float*)d_in[5];
    const float* qw  = (const float*)d_in[6];
    const float* qb  = (const float*)d_in[7];
    const float* kw1 = (const float*)d_in[8];
    const float* kb1 = (const float*)d_in[9];
    const float* kw2 = (const float*)d_in[10];
    const float* kb2 = (const float*)d_in[11];
    const float* vw1 = (const float*)d_in[12];
    const float* vb1 = (const float*)d_in[13];
    const float* vw2 = (const float*)d_in[14];
    const float* vb2 = (const float*)d_in[15];
    const float* ow  = (const float*)d_in[16];
    const float* ob  = (const float*)d_in[17];
    const int* nidx  = (const int*)d_in[18];
    u16* ws16 = (u16*)d_ws;

    prep_pack<<<144, 256, 0, stream>>>(kw1, vw1, kw2, vw2, ws16);
    eqattn_main<<<NBLK, NT, 0, stream>>>(
        bk1,bk2,bv1,bv2, efg, fg, qw,qb, kb1,kb2, vb1,vb2,
        ow,ob, nidx, ws16, (float*)d_out);
}

// Round 10
// 203.976 us; speedup vs baseline: 1.2504x; 1.2504x over previous
//
#include <hip/hip_runtime.h>

typedef unsigned int u32;
typedef unsigned short u16;

#define NT 128
#define NBLK 2500

typedef __attribute__((ext_vector_type(8))) short bh8;
typedef __attribute__((ext_vector_type(4))) float f4;
union U8 { uint4 u; bh8 h; };

__device__ __forceinline__ u16 fb(float x){            // fp32->bf16 RNE (used by prep)
    u32 u = __float_as_uint(x);
    u += 0x7fffu + ((u>>16)&1u);
    return (u16)(u>>16);
}
// pack two f32 -> two bf16 in one VALU op (RNE, same as fb): lo=a, hi=b
__device__ __forceinline__ u32 pk2(float a, float b){
    u32 r;
    __asm__("v_cvt_pk_bf16_f32 %0, %1, %2" : "=v"(r) : "v"(a), "v"(b));
    return r;
}
__device__ __forceinline__ float bf_lo(u32 w){ return __uint_as_float(w<<16); }
__device__ __forceinline__ float bf_hi(u32 w){ return __uint_as_float(w & 0xffff0000u); }

// tanh-form gelu (R7/R8 verified): ~10 VALU + 2 trans; deviation from
// erf-form <= ~4e-4, under the bf16 quantization applied right after.
__device__ __forceinline__ float gelu(float x){
    float x2 = x*x;
    float y  = x * fmaf(0.0356774081f, x2, 0.7978845608f);  // sqrt(2/pi)(x+0.044715x^3)
    float t  = __expf(-2.0f * fabsf(y));                    // e^{-2|y|}
    float r  = __builtin_amdgcn_rcpf(1.0f + t);             // raw v_rcp_f32 (~1ulp)
    float m  = t * r;
    float th = fmaf(-2.0f, m, 1.0f);                        // tanh(|y|)
    float hx = 0.5f * x;
    return fmaf(fabsf(hx), th, hx);                         // 0.5x + 0.5|x|tanh(|y|)
}

// ---------- prep: pack W1^T / W2^T (k and v) into MFMA A-frag order, bf16 ----
// ws16 layout (u16): [A1K:2048][A1V:2048][A2K:16384][A2V:16384]
// (R8 layout — R9's channel permutation REVERTED along with register staging)
__global__ void prep_pack(const float* __restrict__ kw1, const float* __restrict__ vw1,
                          const float* __restrict__ kw2, const float* __restrict__ vw2,
                          u16* __restrict__ ws16)
{
    int t = blockIdx.x*256 + threadIdx.x;        // 0..36863
    if (t >= 36864) return;
    float val;
    if (t < 4096){
        const float* w1 = (t < 2048) ? kw1 : vw1;
        int u = t & 2047;
        int mt = u >> 9, lane = (u>>3)&63, j = u&7;
        int m = mt*16 + (lane&15);
        int x = (lane>>4)*8 + j;
        val = w1[x*64 + m];
    } else {
        int s2 = t - 4096;
        const float* w2 = (s2 < 16384) ? kw2 : vw2;
        int u = s2 & 16383;
        int blkidx = u >> 9;                      // mt*2+s
        int mt = blkidx >> 1, s = blkidx & 1;
        int lane = (u>>3)&63, j = u&7;
        int ij = mt*16 + (lane&15);
        int c  = s*32 + (lane>>4)*8 + j;
        val = w2[c*256 + ij];
    }
    ws16[t] = fb(val);
}

// ---------- one radial conv via MFMA: t2[16] stays in registers ------------
// R8 structure (verified best, 92us): edge tiles in 2 PAIRS (nt = ntp*2+b),
// both tiles staged via LDS h-bounce into disjoint hT halves before one
// lgkm fence; A2/b2g read 2x per conv.
// ROUND-10 delta: tm loads (sTmp) hoisted to conv entry — they depend only
// on the caller's phase-0 fence, NOT the hT staging fence, so they come off
// the post-fence critical path (~120cy x2 ntp).
// Invariants (round-5 + round-1 lessons):
//  - every loop indexing a register array MUST fully unroll;
//  - t2v is written UNCONDITIONALLY via selects (v_cndmask), never under a
//    divergent `if`.
__device__ __forceinline__ void conv_mfma(
    const u16* __restrict__ pA1, const u16* __restrict__ pA2,
    const float* __restrict__ b1g, const float* __restrict__ b2g,
    const bh8* __restrict__ B1f,          // [4] cached ef frags
    const u32* __restrict__ tmpS,         // stride 10 u32 rows (16 bf16)
    u16* __restrict__ hT,                 // this wave's H region: 2 tiles x 1152 u16
    float* __restrict__ t2v,              // [16] regs out
    int w, int lane)
{
    const int r = lane & 15, q = lane >> 4;

    #pragma unroll
    for (int mt=0; mt<16; ++mt) t2v[mt] = 0.f;

    // hoisted W1-bias rows (same 4 addresses were re-read per nt before)
    float4 bva0 = *(const float4*)(b1g +  0 + q*4);
    float4 bva1 = *(const float4*)(b1g + 16 + q*4);
    float4 bva2 = *(const float4*)(b1g + 32 + q*4);
    float4 bva3 = *(const float4*)(b1g + 48 + q*4);

    // hoisted tm loads (all 4 edge tiles) — gated only by phase-0 fence
    uint2 tpA = *(const uint2*)(tmpS + (((w*4+0)*16 + r)*10) + q*2);
    uint2 tpB = *(const uint2*)(tmpS + (((w*4+1)*16 + r)*10) + q*2);
    uint2 tpC = *(const uint2*)(tmpS + (((w*4+2)*16 + r)*10) + q*2);
    uint2 tpD = *(const uint2*)(tmpS + (((w*4+3)*16 + r)*10) + q*2);

    #pragma unroll
    for (int ntp=0; ntp<2; ++ntp){
        bh8 b2f0[2], b2f1[2];
        float tm[2][4];
        {
            uint2 t0 = (ntp==0) ? tpA : tpC;   // folds at compile time
            uint2 t1 = (ntp==0) ? tpB : tpD;
            tm[0][0]=bf_lo(t0.x); tm[0][1]=bf_hi(t0.x);
            tm[0][2]=bf_lo(t0.y); tm[0][3]=bf_hi(t0.y);
            tm[1][0]=bf_lo(t1.x); tm[1][1]=bf_hi(t1.x);
            tm[1][2]=bf_lo(t1.y); tm[1][3]=bf_hi(t1.y);
        }

        // ---- staging: both tiles of the pair -> disjoint hT halves ----
        #pragma unroll
        for (int b=0; b<2; ++b){
            const int nt = ntp*2 + b;
            #pragma unroll
            for (int mt=0; mt<4; ++mt){
                bh8 a1 = *(const bh8*)(pA1 + ((mt*64 + lane)<<3));
                f4 d1 = {0.f,0.f,0.f,0.f};
                d1 = __builtin_amdgcn_mfma_f32_16x16x32_bf16(a1, B1f[nt], d1, 0,0,0);
                float4 bv = (mt==0)?bva0:(mt==1)?bva1:(mt==2)?bva2:bva3;
                float g0 = gelu(d1[0]+bv.x), g1 = gelu(d1[1]+bv.y);
                float g2 = gelu(d1[2]+bv.z), g3 = gelu(d1[3]+bv.w);
                uint2 pk; pk.x = pk2(g0,g1); pk.y = pk2(g2,g3);
                *(uint2*)(hT + b*1152 + r*72 + mt*16 + q*4) = pk;
            }
        }
        // write -> cross-lane-read fence (semantically required)
        __asm__ volatile("s_waitcnt lgkmcnt(0)" ::: "memory");
        #pragma unroll
        for (int b=0; b<2; ++b){
            b2f0[b] = *(const bh8*)(hT + b*1152 + r*72 +      q*8);   // chans q*8..+7
            b2f1[b] = *(const bh8*)(hT + b*1152 + r*72 + 32 + q*8);   // chans 32+q*8..+7
        }

        // ---- main: all 16 ij-tiles, both pair tiles inner ----
        #pragma unroll
        for (int mt=0; mt<16; ++mt){
            bh8 a2s0 = *(const bh8*)(pA2 + (((mt*2+0)*64 + lane)<<3));
            bh8 a2s1 = *(const bh8*)(pA2 + (((mt*2+1)*64 + lane)<<3));
            float4 bv = *(const float4*)(b2g + mt*16 + q*4);
            float pb0, pb1;
            {
                f4 acc = {0.f,0.f,0.f,0.f};
                acc = __builtin_amdgcn_mfma_f32_16x16x32_bf16(a2s0, b2f0[0], acc, 0,0,0);
                acc = __builtin_amdgcn_mfma_f32_16x16x32_bf16(a2s1, b2f1[0], acc, 0,0,0);
                float p = (acc[0]+bv.x)*tm[0][0] + (acc[1]+bv.y)*tm[0][1]
                        + (acc[2]+bv.z)*tm[0][2] + (acc[3]+bv.w)*tm[0][3];
                p += __shfl_xor(p, 16);
                p += __shfl_xor(p, 32);
                pb0 = p;
            }
            {
                f4 acc = {0.f,0.f,0.f,0.f};
                acc = __builtin_amdgcn_mfma_f32_16x16x32_bf16(a2s0, b2f0[1], acc, 0,0,0);
                acc = __builtin_amdgcn_mfma_f32_16x16x32_bf16(a2s1, b2f1[1], acc, 0,0,0);
                float p = (acc[0]+bv.x)*tm[1][0] + (acc[1]+bv.y)*tm[1][1]
                        + (acc[2]+bv.z)*tm[1][2] + (acc[3]+bv.w)*tm[1][3];
                p += __shfl_xor(p, 16);
                p += __shfl_xor(p, 32);
                pb1 = p;
            }
            // owner lane of edge (w*4+nt)*16+r is (q=nt, r); nt = ntp*2 + (q&1)
            float sel = (q & 1) ? pb1 : pb0;
            t2v[mt] = ((q >> 1) == ntp) ? sel : t2v[mt];
        }
    }
}

// ---------------- fused main kernel -------------------------------------------
// ROUND-10 = R8 (92us, verified best) + off-critical-path micro-opts:
//  (a) tm loads hoisted in conv (see conv_mfma);
//  (b) bk2/bv2 epilogue coefficients prefetched at kernel top (independent
//      streams — hides ~600cy HBM/L3 latency under the convs);
//  (c) q=eq_linear moved into phase 0 (depends only on fg/qw) into its own
//      sQ buffer -> one whole phase + one __syncthreads deleted post-conv.
// R9's register-staging REVERTED (VGPR 152 -> serial-chain + occupancy loss).
// launch_bounds(128,1): allocator unconstrained (history: arg2=2 capped arch
// VGPRs at 128 -> 950B/thread spill).
__global__ __launch_bounds__(NT, 1) void eqattn_main(
    const float* __restrict__ bk1, const float* __restrict__ bk2,
    const float* __restrict__ bv1, const float* __restrict__ bv2,
    const float* __restrict__ efg, const float* __restrict__ fg,
    const float* __restrict__ qw,  const float* __restrict__ qb,
    const float* __restrict__ kb1, const float* __restrict__ kb2,
    const float* __restrict__ vb1, const float* __restrict__ vb2,
    const float* __restrict__ ow,  const float* __restrict__ ob,
    const int* __restrict__ nidx,  const u16* __restrict__ ws16,
    float* __restrict__ outg)
{
    __shared__ __align__(16) u32 sTmpK[1280];  // 5120: tmp-k bf16 rows (stride 10 u32) -> attn scratch
    __shared__ __align__(16) u32 sTmpV[1280];  // 5120: tmp-v bf16 rows
    __shared__ __align__(16) u32 sKS [2048];   // 8192: k rows 16 u32 (pair-swizzled)
    __shared__ __align__(16) u32 sVS [2048];   // 8192: v rows
    __shared__ __align__(16) u16 sHT [4608];   // 9216: per-wave H regions (2 waves x 2 tiles x 1152)
    __shared__ __align__(16) float sQ[264];    // 1056: q vectors [8][33] (written in phase 0)

    const int t    = threadIdx.x;
    const int lane = t & 63;
    const int w    = t >> 6;
    const int r    = lane & 15, q = lane >> 4;
    const int n0   = blockIdx.x * 8;
    const int e    = blockIdx.x * 128 + t;

    const u16* pA1k = ws16;
    const u16* pA1v = ws16 + 2048;
    const u16* pA2k = ws16 + 4096;
    const u16* pA2v = ws16 + 20480;

    // ---- prefetch epilogue coefficients (independent streams) ----
    float4 kc0 = *(const float4*)(bk2 + e*8);
    float4 kc1 = *(const float4*)(bk2 + e*8 + 4);
    float4 vc0 = *(const float4*)(bv2 + e*8);
    float4 vc1 = *(const float4*)(bv2 + e*8 + 4);

    // ---- phase 0: gather f[src], tmpk/tmpv (bf16 rows) ----
    {
        int src = nidx[e];
        const float4* fr = (const float4*)(fg + src*32);
        float fs[32];
        #pragma unroll
        for (int i=0;i<8;++i){
            float4 v = fr[i];
            fs[i*4]=v.x; fs[i*4+1]=v.y; fs[i*4+2]=v.z; fs[i*4+3]=v.w;
        }
        float4 ka = *(const float4*)(bk1+e*8), kbv = *(const float4*)(bk1+e*8+4);
        float4 va = *(const float4*)(bv1+e*8), vbv = *(const float4*)(bv1+e*8+4);
        float b1k[8] = {ka.x,ka.y,ka.z,ka.w,kbv.x,kbv.y,kbv.z,kbv.w};
        float b1v[8] = {va.x,va.y,va.z,va.w,vbv.x,vbv.y,vbv.z,vbv.w};
        float tk[16], tv[16];
        #pragma unroll
        for (int m=0;m<8;++m){
            float t0=0.f,t1=0.f,u0=0.f,u1=0.f;
            #pragma unroll
            for (int d=0;d<4;++d){
                float fv = fs[m*4+d];
                t0 += fv*b1k[d*2];  t1 += fv*b1k[d*2+1];
                u0 += fv*b1v[d*2];  u1 += fv*b1v[d*2+1];
            }
            tk[m*2]=t0; tk[m*2+1]=t1; tv[m*2]=u0; tv[m*2+1]=u1;
        }
        #pragma unroll
        for (int i=0;i<8;++i){
            sTmpK[t*10+i] = pk2(tk[i*2], tk[i*2+1]);
            sTmpV[t*10+i] = pk2(tv[i*2], tv[i*2+1]);
        }
    }

    // ---- q = eq_linear(f, q_w, q_b) moved into phase 0 (indep of convs);
    // consumers (logits) read sQ after the post-conv __syncthreads ----
    #pragma unroll 1
    for (int p=0;p<2;++p){
        int task = p*NT + t;
        int ln = task>>5, m=(task>>2)&7, d=task&3;
        const float* frow = fg + (n0+ln)*32;
        int rr = ((d>0)?8:0) + m;
        float acc = (d==0) ? qb[m] : 0.f;
        #pragma unroll
        for (int mm=0;mm<8;++mm) acc += qw[rr*8+mm]*frow[mm*4+d];
        sQ[ln*33 + m*4 + d] = acc;
    }

    // ---- B1 frags: ef rows -> bf16 (shared by K and V convs) ----
    bh8 B1f[4];
    #pragma unroll
    for (int nt=0; nt<4; ++nt){
        int eg = blockIdx.x*128 + (w*4+nt)*16 + r;
        float4 ea = *(const float4*)(efg + eg*32 + q*8);
        float4 eb = *(const float4*)(efg + eg*32 + q*8 + 4);
        U8 uu;
        uu.u.x = pk2(ea.x, ea.y); uu.u.y = pk2(ea.z, ea.w);
        uu.u.z = pk2(eb.x, eb.y); uu.u.w = pk2(eb.z, eb.w);
        B1f[nt] = uu.h;
    }
    // fence: phase-0 sTmp writes (same wave, cross-lane) before tm reads
    __asm__ volatile("s_waitcnt lgkmcnt(0)" ::: "memory");

    u16* hT = sHT + w*2304;

    // ---- K conv ----
    float t2k[16];
    conv_mfma(pA1k, pA2k, kb1, kb2, B1f, sTmpK, hT, t2k, w, lane);
    {
        #pragma unroll
        for (int m=0;m<8;++m){
            float t20 = t2k[2*m], t21 = t2k[2*m+1];
            uint2 pk;
            pk.x = pk2(t20*kc0.x + t21*kc1.x, t20*kc0.y + t21*kc1.y);
            pk.y = pk2(t20*kc0.z + t21*kc1.z, t20*kc0.w + t21*kc1.w);
            *(uint2*)(sKS + t*16 + ((m ^ (t&7))<<1)) = pk;
        }
    }
    // ---- V conv ----
    float t2va[16];
    conv_mfma(pA1v, pA2v, vb1, vb2, B1f, sTmpV, hT, t2va, w, lane);
    {
        #pragma unroll
        for (int m=0;m<8;++m){
            float t20 = t2va[2*m], t21 = t2va[2*m+1];
            uint2 pk;
            pk.x = pk2(t20*vc0.x + t21*vc1.x, t20*vc0.y + t21*vc1.y);
            pk.y = pk2(t20*vc0.z + t21*vc1.z, t20*vc0.w + t21*vc1.w);
            *(uint2*)(sVS + t*16 + ((m ^ (t&7))<<1)) = pk;
        }
    }
    __syncthreads();

    float* lg  = (float*)sTmpK + 264;  // [32][17] = 544 floats (tmp rows dead)
    float* aoS = (float*)sTmpK + 808;  // [8][33] = 264 floats (1072 <= 1280)

    // ---- logits: 512 tasks ----
    #pragma unroll 1
    for (int p=0;p<4;++p){
        int task = p*NT + t;
        int ln = task>>6, hh=(task>>4)&3, k=task&15;
        int row = ln*16 + k;
        const float* qr = sQ + ln*33 + hh*8;
        uint2 k0 = *(const uint2*)(sKS + row*16 + (((hh<<1)     ^ (row&7))<<1));
        uint2 k1 = *(const uint2*)(sKS + row*16 + ((((hh<<1)|1) ^ (row&7))<<1));
        float acc = qr[0]*bf_lo(k0.x)+qr[1]*bf_hi(k0.x)
                  + qr[2]*bf_lo(k0.y)+qr[3]*bf_hi(k0.y)
                  + qr[4]*bf_lo(k1.x)+qr[5]*bf_hi(k1.x)
                  + qr[6]*bf_lo(k1.y)+qr[7]*bf_hi(k1.y);
        lg[(ln*4+hh)*17 + k] = acc * 0.35355339059327373f;
    }
    __syncthreads();

    // ---- softmax over 16 neighbors: parallel (4 lanes/row, all 128 threads;
    // shfl groups stay inside one wave) ----
    {
        int row = t >> 2, sub = t & 3;
        float* rp = lg + row*17 + sub*4;
        float a0=rp[0], a1=rp[1], a2=rp[2], a3=rp[3];
        float mx = fmaxf(fmaxf(a0,a1), fmaxf(a2,a3));
        mx = fmaxf(mx, __shfl_xor(mx, 1));
        mx = fmaxf(mx, __shfl_xor(mx, 2));
        float e0=__expf(a0-mx), e1=__expf(a1-mx);
        float e2=__expf(a2-mx), e3=__expf(a3-mx);
        float s = (e0+e1)+(e2+e3);
        s += __shfl_xor(s, 1);
        s += __shfl_xor(s, 2);
        float inv = __builtin_amdgcn_rcpf(s);
        // one Newton step to keep softmax normalization at fp32 accuracy
        inv = inv * (2.0f - s*inv);
        rp[0]=e0*inv; rp[1]=e1*inv; rp[2]=e2*inv; rp[3]=e3*inv;
    }
    __syncthreads();

    // ---- attention output: 256 tasks ----
    #pragma unroll 1
    for (int p=0;p<2;++p){
        int task = p*NT + t;
        int ln = task>>5, comp = task&31, hh = comp>>3;
        const float* ar = lg + (ln*4+hh)*17;
        float acc=0.f;
        #pragma unroll
        for (int k=0;k<16;++k){
            int row = ln*16 + k;
            u32 wv = sVS[row*16 + (((comp>>2) ^ (row&7))<<1) + ((comp>>1)&1)];
            acc += ar[k] * ((comp&1) ? bf_hi(wv) : bf_lo(wv));
        }
        aoS[ln*33 + comp] = acc;
    }
    __syncthreads();

    // ---- final eq_linear(o_w, o_b) -> fp32 out ----
    #pragma unroll 1
    for (int p=0;p<2;++p){
        int task = p*NT + t;
        int ln = task>>5, m=(task>>2)&7, d=task&3;
        int rr = ((d>0)?8:0) + m;
        float acc = (d==0) ? ob[m] : 0.f;
        #pragma unroll
        for (int mm=0;mm<8;++mm) acc += ow[rr*8+mm]*aoS[ln*33 + mm*4 + d];
        outg[(n0+ln)*32 + m*4 + d] = acc;
    }
}

extern "C" void kernel_launch(void* const* d_in, const int* in_sizes, int n_in,
                              void* d_out, int out_size, void* d_ws, size_t ws_size,
                              hipStream_t stream)
{
    (void)in_sizes; (void)n_in; (void)out_size; (void)ws_size;
    const float* bk1 = (const float*)d_in[0];
    const float* bk2 = (const float*)d_in[1];
    const float* bv1 = (const float*)d_in[2];
    const float* bv2 = (const float*)d_in[3];
    const float* efg = (const float*)d_in[4];
    const float* fg  = (const float*)d_in[5];
    const float* qw  = (const float*)d_in[6];
    const float* qb  = (const float*)d_in[7];
    const float* kw1 = (const float*)d_in[8];
    const float* kb1 = (const float*)d_in[9];
    const float* kw2 = (const float*)d_in[10];
    const float* kb2 = (const float*)d_in[11];
    const float* vw1 = (const float*)d_in[12];
    const float* vb1 = (const float*)d_in[13];
    const float* vw2 = (const float*)d_in[14];
    const float* vb2 = (const float*)d_in[15];
    const float* ow  = (const float*)d_in[16];
    const float* ob  = (const float*)d_in[17];
    const int* nidx  = (const int*)d_in[18];
    u16* ws16 = (u16*)d_ws;

    prep_pack<<<144, 256, 0, stream>>>(kw1, vw1, kw2, vw2, ws16);
    eqattn_main<<<NBLK, NT, 0, stream>>>(
        bk1,bk2,bv1,bv2, efg, fg, qw,qb, kb1,kb2, vb1,vb2,
        ow,ob, nidx, ws16, (float*)d_out);
}